// Round 1
// baseline (634.282 us; speedup 1.0000x reference)
//
#include <hip/hip_runtime.h>
#include <math.h>

#define TWOPI 6.283185307179586f
// pad every 32 floats to break stride-2^k bank patterns
#define PD(i) ((i) + ((i) >> 5))

__device__ inline float gelu_f(float x) {
    return 0.5f * x * (1.0f + erff(x * 0.70710678118654752f));
}

// ---------- 8-point DFT in registers. S=-1 forward, S=+1 inverse ----------
template<int S>
__device__ inline void fft8(float* xr, float* xi) {
    const float C = 0.70710678118654752f;
    float c0r=xr[0]+xr[4], c0i=xi[0]+xi[4];
    float c1r=xr[1]+xr[5], c1i=xi[1]+xi[5];
    float c2r=xr[2]+xr[6], c2i=xi[2]+xi[6];
    float c3r=xr[3]+xr[7], c3i=xi[3]+xi[7];
    float d0r=xr[0]-xr[4], d0i=xi[0]-xi[4];
    float t1r=xr[1]-xr[5], t1i=xi[1]-xi[5];
    float t2r=xr[2]-xr[6], t2i=xi[2]-xi[6];
    float t3r=xr[3]-xr[7], t3i=xi[3]-xi[7];
    // d1 = t1 * w^1, w = C*(1 + iS)
    float d1r = C*(t1r - S*t1i), d1i = C*(S*t1r + t1i);
    // d2 = t2 * (iS)
    float d2r = -S*t2i, d2i = S*t2r;
    // d3 = t3 * w^3, w^3 = C*(-1 + iS)
    float d3r = C*(-t3r - S*t3i), d3i = C*(S*t3r - t3i);
    // DFT4 on c -> X0,X2,X4,X6
    float e0r=c0r+c2r, e0i=c0i+c2i, e1r=c1r+c3r, e1i=c1i+c3i;
    float f0r=c0r-c2r, f0i=c0i-c2i, f1r=c1r-c3r, f1i=c1i-c3i;
    xr[0]=e0r+e1r; xi[0]=e0i+e1i;
    xr[4]=e0r-e1r; xi[4]=e0i-e1i;
    xr[2]=f0r - S*f1i; xi[2]=f0i + S*f1r;
    xr[6]=f0r + S*f1i; xi[6]=f0i - S*f1r;
    // DFT4 on d -> X1,X3,X5,X7
    e0r=d0r+d2r; e0i=d0i+d2i; e1r=d1r+d3r; e1i=d1i+d3i;
    f0r=d0r-d2r; f0i=d0i-d2i; f1r=d1r-d3r; f1i=d1i-d3i;
    xr[1]=e0r+e1r; xi[1]=e0i+e1i;
    xr[5]=e0r-e1r; xi[5]=e0i-e1i;
    xr[3]=f0r - S*f1i; xi[3]=f0i + S*f1r;
    xr[7]=f0r + S*f1i; xi[7]=f0i - S*f1r;
}

template<int S>
__device__ inline void fft4(float* xr, float* xi) {
    float e0r=xr[0]+xr[2], e0i=xi[0]+xi[2];
    float e1r=xr[1]+xr[3], e1i=xi[1]+xi[3];
    float f0r=xr[0]-xr[2], f0i=xi[0]-xi[2];
    float f1r=xr[1]-xr[3], f1i=xi[1]-xi[3];
    xr[0]=e0r+e1r; xi[0]=e0i+e1i;
    xr[2]=e0r-e1r; xi[2]=e0i-e1i;
    xr[1]=f0r - S*f1i; xi[1]=f0i + S*f1r;
    xr[3]=f0r + S*f1i; xi[3]=f0i - S*f1r;
}

// ---------- one Stockham radix-8 stage: src -> dst. n=2048, 256 threads ----------
// reads at p + r*256; writes at k + 8*j*m + q*m; j = p>>lm, k = p & (m-1)
template<int S>
__device__ inline void stage8(const float* sr, const float* si, float* dr, float* di,
                              int t, int lm, float dinv) {
    float xr[8], xi[8];
#pragma unroll
    for (int r = 0; r < 8; r++) {
        int idx = t + (r << 8);
        xr[r] = sr[PD(idx)]; xi[r] = si[PD(idx)];
    }
    fft8<S>(xr, xi);
    int j = t >> lm;
    int kk = t & ((1 << lm) - 1);
    int base = (j << (lm + 3)) + kk;
    float ang = (float)S * TWOPI * (float)j * dinv;
    float ws, wc;
    __sincosf(ang, &ws, &wc);
    float cr = 1.f, ci = 0.f;
#pragma unroll
    for (int q = 0; q < 8; q++) {
        float vr = xr[q]*cr - xi[q]*ci;
        float vi = xr[q]*ci + xi[q]*cr;
        int a = base + (q << lm);
        dr[PD(a)] = vr; di[PD(a)] = vi;
        float ncr = cr*wc - ci*ws;
        ci = cr*ws + ci*wc; cr = ncr;
    }
}

// ---------- final radix-4 stage (m=512, l=1 -> no twiddles) ----------
template<int S>
__device__ inline void stage4(const float* sr, const float* si, float* dr, float* di, int t) {
#pragma unroll
    for (int h2 = 0; h2 < 2; h2++) {
        int p = t + (h2 << 8);
        float xr[4], xi[4];
#pragma unroll
        for (int r = 0; r < 4; r++) {
            int idx = p + (r << 9);
            xr[r] = sr[PD(idx)]; xi[r] = si[PD(idx)];
        }
        fft4<S>(xr, xi);
#pragma unroll
        for (int q = 0; q < 4; q++) {
            int a = p + (q << 9);
            dr[PD(a)] = xr[q]; di[PD(a)] = xi[q];
        }
    }
}

// =========== kernel A: context sums (atomic partial reduction over N) ===========
__global__ __launch_bounds__(256) void ctx_kernel(const float* __restrict__ x,
                                                  float* __restrict__ ctx) {
    int d = blockIdx.x * 256 + threadIdx.x;   // 0..767
    int nc = blockIdx.y;                      // 0..31 (chunks of 64 rows)
    int b = blockIdx.z;
    const float* xp = x + ((size_t)b * 2048 + nc * 64) * 768 + d;
    float acc = 0.f;
#pragma unroll 4
    for (int r = 0; r < 64; r++) acc += xp[(size_t)r * 768];
    atomicAdd(&ctx[b * 768 + d], acc);
}

// =========== kernel B1: t = gelu(mean_ctx @ w1 + b1) ===========
__global__ __launch_bounds__(256) void mlp1_kernel(const float* __restrict__ ctx,
                                                   const float* __restrict__ w1,
                                                   const float* __restrict__ b1,
                                                   float* __restrict__ tbuf) {
    __shared__ float cm[768];
    int b = blockIdx.y;
    int jg = blockIdx.x * 256 + threadIdx.x;
    for (int k = threadIdx.x; k < 768; k += 256)
        cm[k] = ctx[b * 768 + k] * (1.0f / 2048.0f);
    __syncthreads();
    float acc = b1[jg];
    for (int k = 0; k < 768; k++)
        acc = fmaf(cm[k], w1[k * 768 + jg], acc);
    tbuf[b * 768 + jg] = gelu_f(acc);
}

// =========== kernel B2: mod = t @ w2 + b2 (k split into 4, atomic accumulate) ===========
__global__ __launch_bounds__(256) void mlp2_kernel(const float* __restrict__ tbuf,
                                                   const float* __restrict__ w2,
                                                   const float* __restrict__ b2,
                                                   float* __restrict__ mod) {
    __shared__ float tl[16][192];
    int m = blockIdx.x * 256 + threadIdx.x;   // 0..24575
    int kc = blockIdx.y;                      // 0..3
    int k0 = kc * 192;
    for (int idx = threadIdx.x; idx < 16 * 192; idx += 256) {
        int bb = idx / 192, kk = idx % 192;
        tl[bb][kk] = tbuf[bb * 768 + k0 + kk];
    }
    __syncthreads();
    float acc[16];
#pragma unroll
    for (int bb = 0; bb < 16; bb++) acc[bb] = 0.f;
    for (int kk = 0; kk < 192; kk++) {
        float wv = w2[(size_t)(k0 + kk) * 24576 + m];
#pragma unroll
        for (int bb = 0; bb < 16; bb++) acc[bb] = fmaf(tl[bb][kk], wv, acc[bb]);
    }
    float bias = (kc == 0) ? b2[m] : 0.f;
#pragma unroll
    for (int bb = 0; bb < 16; bb++)
        atomicAdd(&mod[bb * 24576 + m], acc[bb] + bias);
}

// =========== kernel C: FFT -> filter+GELU -> IFFT -> y = x + xf ===========
// one block per (pair, h, b); two real channels packed per complex FFT
__global__ __launch_bounds__(256) void spectral_kernel(const float* __restrict__ x,
                                                       const float* __restrict__ bf,
                                                       const float* __restrict__ mod,
                                                       float* __restrict__ y) {
    __shared__ float Ar[2112], Ai[2112], Br[2112], Bi[2112];
    int t = threadIdx.x;
    int pair = blockIdx.x;    // 0..31
    int h = blockIdx.y;       // 0..11
    int b = blockIdx.z;       // 0..15
    int d0 = h * 64 + pair * 2;
    const float* xb = x + (size_t)b * 2048 * 768 + d0;

    float zx[8], zy[8];
#pragma unroll
    for (int u = 0; u < 8; u++) {
        int n = t + (u << 8);
        float2 v = *(const float2*)(xb + (size_t)n * 768);
        zx[u] = v.x; zy[u] = v.y;
        Ar[PD(n)] = v.x; Ai[PD(n)] = v.y;
    }
    __syncthreads();
    // forward FFT: A -> B -> A -> B -> A
    stage8<-1>(Ar, Ai, Br, Bi, t, 0, 1.0f / 2048.0f); __syncthreads();
    stage8<-1>(Br, Bi, Ar, Ai, t, 3, 1.0f / 256.0f);  __syncthreads();
    stage8<-1>(Ar, Ai, Br, Bi, t, 6, 1.0f / 32.0f);   __syncthreads();
    stage4<-1>(Br, Bi, Ar, Ai, t);                    __syncthreads();

    // spectral step: Z in A. Separate pair spectra, filter+GELU, recombine -> W in B
    const float* bfh = bf + h * 2048;
    const float* modh = mod + ((size_t)b * 12 + h) * 2048;
    const float sc = 0.5f / 2048.0f;  // Hermitian 0.5 * (1/N) ifft normalization
    for (int u = 0; u < 5; u++) {
        int i;
        if (u < 4) i = t + (u << 8);
        else { if (t != 0) break; i = 1024; }    // self-paired Nyquist bin
        int mi = (2048 - i) & 2047;
        float Zr = Ar[PD(i)],  Zi = Ai[PD(i)];
        float Mr = Ar[PD(mi)], Mi = Ai[PD(mi)];
        // channel spectra (Hermitian): F1 = (Z + conj(Zm))/2 ; F2 = (Z - conj(Zm))/(2i)
        float F1r = 0.5f * (Zr + Mr), F1i = 0.5f * (Zi - Mi);
        float F2r = 0.5f * (Zi + Mi), F2i = 0.5f * (Mr - Zr);
        float fi = bfh[i] + modh[i];
        float fm = bfh[mi] + modh[mi];
        // G = gelu(Re(F)*filt) + i gelu(Im(F)*filt); F[mi] = conj(F[i])
        float G1ri = gelu_f(F1r * fi), G1ii = gelu_f(F1i * fi);
        float G2ri = gelu_f(F2r * fi), G2ii = gelu_f(F2i * fi);
        float G1rm = gelu_f(F1r * fm), G1im = gelu_f(-F1i * fm);
        float G2rm = gelu_f(F2r * fm), G2im = gelu_f(-F2i * fm);
        // W = Herm(G1) + i*Herm(G2)  (scaled by 1/N)
        float Wr_i = sc * ((G1ri + G1rm) - (G2ii - G2im));
        float Wi_i = sc * ((G1ii - G1im) + (G2ri + G2rm));
        float Wr_m = sc * ((G1rm + G1ri) - (G2im - G2ii));
        float Wi_m = sc * ((G1im - G1ii) + (G2rm + G2ri));
        Br[PD(i)] = Wr_i;  Bi[PD(i)] = Wi_i;
        Br[PD(mi)] = Wr_m; Bi[PD(mi)] = Wi_m;
    }
    __syncthreads();
    // inverse FFT: B -> A -> B -> A -> B
    stage8<1>(Br, Bi, Ar, Ai, t, 0, 1.0f / 2048.0f); __syncthreads();
    stage8<1>(Ar, Ai, Br, Bi, t, 3, 1.0f / 256.0f);  __syncthreads();
    stage8<1>(Br, Bi, Ar, Ai, t, 6, 1.0f / 32.0f);   __syncthreads();
    stage4<1>(Ar, Ai, Br, Bi, t);                    __syncthreads();
    // y = x + ifft real parts (Re -> channel d0, Im -> channel d0+1)
    float* yb = y + (size_t)b * 2048 * 768 + d0;
#pragma unroll
    for (int u = 0; u < 8; u++) {
        int n = t + (u << 8);
        float2 v;
        v.x = zx[u] + Br[PD(n)];
        v.y = zy[u] + Bi[PD(n)];
        *(float2*)(yb + (size_t)n * 768) = v;
    }
}

// =========== kernel D: LayerNorm in place, one wave per row of 768 ===========
__global__ __launch_bounds__(256) void ln_kernel(float* __restrict__ y,
                                                 const float* __restrict__ g,
                                                 const float* __restrict__ bet) {
    int wave = threadIdx.x >> 6;
    int lane = threadIdx.x & 63;
    size_t row = (size_t)blockIdx.x * 4 + wave;  // < 32768
    float* yp = y + row * 768;
    float4 v[3];
    float s = 0.f, s2 = 0.f;
#pragma unroll
    for (int u = 0; u < 3; u++) {
        v[u] = *(const float4*)(yp + u * 256 + lane * 4);
        s  += v[u].x + v[u].y + v[u].z + v[u].w;
        s2 += v[u].x * v[u].x + v[u].y * v[u].y + v[u].z * v[u].z + v[u].w * v[u].w;
    }
#pragma unroll
    for (int off = 32; off > 0; off >>= 1) {
        s  += __shfl_down(s, off);
        s2 += __shfl_down(s2, off);
    }
    s = __shfl(s, 0); s2 = __shfl(s2, 0);
    float mu = s * (1.0f / 768.0f);
    float var = s2 * (1.0f / 768.0f) - mu * mu;
    float rs = rsqrtf(var + 1e-5f);
#pragma unroll
    for (int u = 0; u < 3; u++) {
        int d = u * 256 + lane * 4;
        float4 gv = *(const float4*)(g + d);
        float4 bv = *(const float4*)(bet + d);
        float4 o;
        o.x = (v[u].x - mu) * rs * gv.x + bv.x;
        o.y = (v[u].y - mu) * rs * gv.y + bv.y;
        o.z = (v[u].z - mu) * rs * gv.z + bv.z;
        o.w = (v[u].w - mu) * rs * gv.w + bv.w;
        *(float4*)(yp + d) = o;
    }
}

extern "C" void kernel_launch(void* const* d_in, const int* in_sizes, int n_in,
                              void* d_out, int out_size, void* d_ws, size_t ws_size,
                              hipStream_t stream) {
    const float* x   = (const float*)d_in[0];
    const float* bf  = (const float*)d_in[1];
    const float* w1  = (const float*)d_in[2];
    const float* b1  = (const float*)d_in[3];
    const float* w2  = (const float*)d_in[4];
    const float* b2  = (const float*)d_in[5];
    const float* lng = (const float*)d_in[6];
    const float* lnb = (const float*)d_in[7];
    float* out = (float*)d_out;

    float* ctx  = (float*)d_ws;            // 16*768
    float* tbuf = ctx + 16 * 768;          // 16*768
    float* mod  = tbuf + 16 * 768;         // 16*24576

    hipMemsetAsync(ctx, 0, 16 * 768 * sizeof(float), stream);
    hipMemsetAsync(mod, 0, (size_t)16 * 24576 * sizeof(float), stream);

    ctx_kernel<<<dim3(3, 32, 16), 256, 0, stream>>>(x, ctx);
    mlp1_kernel<<<dim3(3, 16), 256, 0, stream>>>(ctx, w1, b1, tbuf);
    mlp2_kernel<<<dim3(96, 4), 256, 0, stream>>>(tbuf, w2, b2, mod);
    spectral_kernel<<<dim3(32, 12, 16), 256, 0, stream>>>(x, bf, mod, out);
    ln_kernel<<<8192, 256, 0, stream>>>(out, lng, lnb);
}

// Round 3
// 442.977 us; speedup vs baseline: 1.4319x; 1.4319x over previous
//
#include <hip/hip_runtime.h>
#include <math.h>

#define TWOPI 6.283185307179586f
// pad every 32 floats to break stride-2^k bank patterns
#define PD(i) ((i) + ((i) >> 5))

__device__ inline float gelu_f(float x) {
    return 0.5f * x * (1.0f + erff(x * 0.70710678118654752f));
}

// ---------- 8-point DFT in registers. S=-1 forward, S=+1 inverse ----------
template<int S>
__device__ inline void fft8(float* xr, float* xi) {
    const float C = 0.70710678118654752f;
    float c0r=xr[0]+xr[4], c0i=xi[0]+xi[4];
    float c1r=xr[1]+xr[5], c1i=xi[1]+xi[5];
    float c2r=xr[2]+xr[6], c2i=xi[2]+xi[6];
    float c3r=xr[3]+xr[7], c3i=xi[3]+xi[7];
    float d0r=xr[0]-xr[4], d0i=xi[0]-xi[4];
    float t1r=xr[1]-xr[5], t1i=xi[1]-xi[5];
    float t2r=xr[2]-xr[6], t2i=xi[2]-xi[6];
    float t3r=xr[3]-xr[7], t3i=xi[3]-xi[7];
    float d1r = C*(t1r - S*t1i), d1i = C*(S*t1r + t1i);
    float d2r = -S*t2i, d2i = S*t2r;
    float d3r = C*(-t3r - S*t3i), d3i = C*(S*t3r - t3i);
    float e0r=c0r+c2r, e0i=c0i+c2i, e1r=c1r+c3r, e1i=c1i+c3i;
    float f0r=c0r-c2r, f0i=c0i-c2i, f1r=c1r-c3r, f1i=c1i-c3i;
    xr[0]=e0r+e1r; xi[0]=e0i+e1i;
    xr[4]=e0r-e1r; xi[4]=e0i-e1i;
    xr[2]=f0r - S*f1i; xi[2]=f0i + S*f1r;
    xr[6]=f0r + S*f1i; xi[6]=f0i - S*f1r;
    e0r=d0r+d2r; e0i=d0i+d2i; e1r=d1r+d3r; e1i=d1i+d3i;
    f0r=d0r-d2r; f0i=d0i-d2i; f1r=d1r-d3r; f1i=d1i-d3i;
    xr[1]=e0r+e1r; xi[1]=e0i+e1i;
    xr[5]=e0r-e1r; xi[5]=e0i-e1i;
    xr[3]=f0r - S*f1i; xi[3]=f0i + S*f1r;
    xr[7]=f0r + S*f1i; xi[7]=f0i - S*f1r;
}

template<int S>
__device__ inline void fft4(float* xr, float* xi) {
    float e0r=xr[0]+xr[2], e0i=xi[0]+xi[2];
    float e1r=xr[1]+xr[3], e1i=xi[1]+xi[3];
    float f0r=xr[0]-xr[2], f0i=xi[0]-xi[2];
    float f1r=xr[1]-xr[3], f1i=xi[1]-xi[3];
    xr[0]=e0r+e1r; xi[0]=e0i+e1i;
    xr[2]=e0r-e1r; xi[2]=e0i-e1i;
    xr[1]=f0r - S*f1i; xi[1]=f0i + S*f1r;
    xr[3]=f0r + S*f1i; xi[3]=f0i - S*f1r;
}

// ---------- one Stockham radix-8 stage: src -> dst. n=2048, 256 threads ----------
template<int S>
__device__ inline void stage8(const float* sr, const float* si, float* dr, float* di,
                              int t, int lm, float dinv) {
    float xr[8], xi[8];
#pragma unroll
    for (int r = 0; r < 8; r++) {
        int idx = t + (r << 8);
        xr[r] = sr[PD(idx)]; xi[r] = si[PD(idx)];
    }
    fft8<S>(xr, xi);
    int j = t >> lm;
    int kk = t & ((1 << lm) - 1);
    int base = (j << (lm + 3)) + kk;
    float ang = (float)S * TWOPI * (float)j * dinv;
    float ws, wc;
    __sincosf(ang, &ws, &wc);
    float cr = 1.f, ci = 0.f;
#pragma unroll
    for (int q = 0; q < 8; q++) {
        float vr = xr[q]*cr - xi[q]*ci;
        float vi = xr[q]*ci + xi[q]*cr;
        int a = base + (q << lm);
        dr[PD(a)] = vr; di[PD(a)] = vi;
        float ncr = cr*wc - ci*ws;
        ci = cr*ws + ci*wc; cr = ncr;
    }
}

// ---------- final radix-4 stage (m=512 -> no twiddles) ----------
template<int S>
__device__ inline void stage4(const float* sr, const float* si, float* dr, float* di, int t) {
#pragma unroll
    for (int h2 = 0; h2 < 2; h2++) {
        int p = t + (h2 << 8);
        float xr[4], xi[4];
#pragma unroll
        for (int r = 0; r < 4; r++) {
            int idx = p + (r << 9);
            xr[r] = sr[PD(idx)]; xi[r] = si[PD(idx)];
        }
        fft4<S>(xr, xi);
#pragma unroll
        for (int q = 0; q < 4; q++) {
            int a = p + (q << 9);
            dr[PD(a)] = xr[q]; di[PD(a)] = xi[q];
        }
    }
}

// =========== kernel T1: 64x64 tiled transpose x[b,n,d] -> xT[b,d,n], fused ctx sums ===========
__global__ __launch_bounds__(256) void transpose_ctx_kernel(const float* __restrict__ x,
                                                            float* __restrict__ xT,
                                                            float* __restrict__ ctx) {
    __shared__ float tile[64][65];
    __shared__ float csum[4][64];
    int t = threadIdx.x;
    int d0 = blockIdx.x * 64;   // 12
    int n0 = blockIdx.y * 64;   // 32
    int b  = blockIdx.z;        // 16
    // load 64 rows x 64 cols, float4 per thread, 4 iters
#pragma unroll
    for (int r = 0; r < 4; r++) {
        int flat = r * 256 + t;
        int nn = flat >> 4;          // 0..63
        int q  = flat & 15;          // 0..15
        float4 v = *(const float4*)(x + ((size_t)(b * 2048 + n0 + nn) * 768) + d0 + q * 4);
        tile[nn][q * 4 + 0] = v.x;
        tile[nn][q * 4 + 1] = v.y;
        tile[nn][q * 4 + 2] = v.z;
        tile[nn][q * 4 + 3] = v.w;
    }
    __syncthreads();
    // ctx partial sums: column sums over the 64 n-rows
    {
        int dd = t & 63, part = t >> 6;
        float s = 0.f;
#pragma unroll
        for (int r = 0; r < 16; r++) s += tile[part * 16 + r][dd];
        csum[part][dd] = s;
    }
    // transposed write
#pragma unroll
    for (int r = 0; r < 4; r++) {
        int flat = r * 256 + t;
        int dd = flat >> 4;          // 0..63
        int nq = flat & 15;          // 0..15
        float4 o;
        o.x = tile[nq * 4 + 0][dd];
        o.y = tile[nq * 4 + 1][dd];
        o.z = tile[nq * 4 + 2][dd];
        o.w = tile[nq * 4 + 3][dd];
        *(float4*)(xT + ((size_t)b * 768 + d0 + dd) * 2048 + n0 + nq * 4) = o;
    }
    __syncthreads();
    if (t < 64) {
        float tot = csum[0][t] + csum[1][t] + csum[2][t] + csum[3][t];
        atomicAdd(&ctx[b * 768 + d0 + t], tot);
    }
}

// =========== kernel B1: t = gelu(mean_ctx @ w1 + b1) ===========
__global__ __launch_bounds__(256) void mlp1_kernel(const float* __restrict__ ctx,
                                                   const float* __restrict__ w1,
                                                   const float* __restrict__ b1,
                                                   float* __restrict__ tbuf) {
    __shared__ float cm[768];
    int b = blockIdx.y;
    int jg = blockIdx.x * 256 + threadIdx.x;
    for (int k = threadIdx.x; k < 768; k += 256)
        cm[k] = ctx[b * 768 + k] * (1.0f / 2048.0f);
    __syncthreads();
    float acc = b1[jg];
    for (int k = 0; k < 768; k++)
        acc = fmaf(cm[k], w1[k * 768 + jg], acc);
    tbuf[b * 768 + jg] = gelu_f(acc);
}

// =========== kernel B2: mod = t @ w2 + b2 (k split into 4, atomic accumulate) ===========
__global__ __launch_bounds__(256) void mlp2_kernel(const float* __restrict__ tbuf,
                                                   const float* __restrict__ w2,
                                                   const float* __restrict__ b2,
                                                   float* __restrict__ mod) {
    __shared__ float tl[16][192];
    int m = blockIdx.x * 256 + threadIdx.x;   // 0..24575
    int kc = blockIdx.y;                      // 0..3
    int k0 = kc * 192;
    for (int idx = threadIdx.x; idx < 16 * 192; idx += 256) {
        int bb = idx / 192, kk = idx % 192;
        tl[bb][kk] = tbuf[bb * 768 + k0 + kk];
    }
    __syncthreads();
    float acc[16];
#pragma unroll
    for (int bb = 0; bb < 16; bb++) acc[bb] = 0.f;
    for (int kk = 0; kk < 192; kk++) {
        float wv = w2[(size_t)(k0 + kk) * 24576 + m];
#pragma unroll
        for (int bb = 0; bb < 16; bb++) acc[bb] = fmaf(tl[bb][kk], wv, acc[bb]);
    }
    float bias = (kc == 0) ? b2[m] : 0.f;
#pragma unroll
    for (int bb = 0; bb < 16; bb++)
        atomicAdd(&mod[bb * 24576 + m], acc[bb] + bias);
}

// =========== kernel C: FFT -> filter+GELU -> IFFT -> yT = xT + xfT (in place) ===========
__global__ __launch_bounds__(256) void spectral_kernel(float* __restrict__ xT,
                                                       const float* __restrict__ bf,
                                                       const float* __restrict__ mod) {
    __shared__ float Ar[2112], Ai[2112], Br[2112], Bi[2112];
    int t = threadIdx.x;
    int pair = blockIdx.x;    // 0..31
    int h = blockIdx.y;       // 0..11
    int b = blockIdx.z;       // 0..15
    int ch0 = h * 64 + pair * 2;
    float* r0 = xT + ((size_t)b * 768 + ch0) * 2048;
    float* r1 = r0 + 2048;

    float zx[8], zy[8];
#pragma unroll
    for (int u = 0; u < 2; u++) {
        int n = t * 4 + (u << 10);
        float4 a = *(const float4*)(r0 + n);
        float4 c = *(const float4*)(r1 + n);
#pragma unroll
        for (int j = 0; j < 4; j++) {
            float av = (&a.x)[j], cv = (&c.x)[j];
            zx[u * 4 + j] = av; zy[u * 4 + j] = cv;
            Ar[PD(n + j)] = av; Ai[PD(n + j)] = cv;
        }
    }
    __syncthreads();
    // forward FFT: A -> B -> A -> B -> A
    stage8<-1>(Ar, Ai, Br, Bi, t, 0, 1.0f / 2048.0f); __syncthreads();
    stage8<-1>(Br, Bi, Ar, Ai, t, 3, 1.0f / 256.0f);  __syncthreads();
    stage8<-1>(Ar, Ai, Br, Bi, t, 6, 1.0f / 32.0f);   __syncthreads();
    stage4<-1>(Br, Bi, Ar, Ai, t);                    __syncthreads();

    // spectral step: Z in A. Separate pair spectra, filter+GELU, recombine -> W in B
    const float* bfh = bf + h * 2048;
    const float* modh = mod + ((size_t)b * 12 + h) * 2048;
    const float sc = 0.5f / 2048.0f;
    for (int u = 0; u < 5; u++) {
        int i;
        if (u < 4) i = t + (u << 8);
        else { if (t != 0) break; i = 1024; }    // self-paired Nyquist bin
        int mi = (2048 - i) & 2047;
        float Zr = Ar[PD(i)],  Zi = Ai[PD(i)];
        float Mr = Ar[PD(mi)], Mi = Ai[PD(mi)];
        float F1r = 0.5f * (Zr + Mr), F1i = 0.5f * (Zi - Mi);
        float F2r = 0.5f * (Zi + Mi), F2i = 0.5f * (Mr - Zr);
        float fi = bfh[i] + modh[i];
        float fm = bfh[mi] + modh[mi];
        float G1ri = gelu_f(F1r * fi), G1ii = gelu_f(F1i * fi);
        float G2ri = gelu_f(F2r * fi), G2ii = gelu_f(F2i * fi);
        float G1rm = gelu_f(F1r * fm), G1im = gelu_f(-F1i * fm);
        float G2rm = gelu_f(F2r * fm), G2im = gelu_f(-F2i * fm);
        float Wr_i = sc * ((G1ri + G1rm) - (G2ii - G2im));
        float Wi_i = sc * ((G1ii - G1im) + (G2ri + G2rm));
        float Wr_m = sc * ((G1rm + G1ri) - (G2im - G2ii));
        float Wi_m = sc * ((G1im - G1ii) + (G2rm + G2ri));
        Br[PD(i)] = Wr_i;  Bi[PD(i)] = Wi_i;
        Br[PD(mi)] = Wr_m; Bi[PD(mi)] = Wi_m;
    }
    __syncthreads();
    // inverse FFT: B -> A -> B -> A -> B
    stage8<1>(Br, Bi, Ar, Ai, t, 0, 1.0f / 2048.0f); __syncthreads();
    stage8<1>(Ar, Ai, Br, Bi, t, 3, 1.0f / 256.0f);  __syncthreads();
    stage8<1>(Br, Bi, Ar, Ai, t, 6, 1.0f / 32.0f);   __syncthreads();
    stage4<1>(Ar, Ai, Br, Bi, t);                    __syncthreads();
    // yT = xT + ifft real parts (Re -> ch0, Im -> ch0+1), coalesced in-place write
#pragma unroll
    for (int u = 0; u < 2; u++) {
        int n = t * 4 + (u << 10);
        float4 o0, o1;
#pragma unroll
        for (int j = 0; j < 4; j++) {
            (&o0.x)[j] = zx[u * 4 + j] + Br[PD(n + j)];
            (&o1.x)[j] = zy[u * 4 + j] + Bi[PD(n + j)];
        }
        *(float4*)(r0 + n) = o0;
        *(float4*)(r1 + n) = o1;
    }
}

// =========== kernel D: LN. Block = (b, 16 n-rows); reads yT tiles, writes out[b,n,d] ===========
__global__ __launch_bounds__(256) void ln_kernel(const float* __restrict__ yT,
                                                 const float* __restrict__ g,
                                                 const float* __restrict__ bet,
                                                 float* __restrict__ out) {
    __shared__ float tile[768][17];   // 52.2 KB, pad 17 -> conflict-free column reads
    int t = threadIdx.x;
    int n0 = blockIdx.x * 16;         // 128 blocks
    int b = blockIdx.y;               // 16
    // stage yT[b, :, n0:n0+16]
    for (int idx = t; idx < 3072; idx += 256) {
        int d = idx >> 2, nq = idx & 3;
        float4 v = *(const float4*)(yT + ((size_t)b * 768 + d) * 2048 + n0 + nq * 4);
        tile[d][nq * 4 + 0] = v.x;
        tile[d][nq * 4 + 1] = v.y;
        tile[d][nq * 4 + 2] = v.z;
        tile[d][nq * 4 + 3] = v.w;
    }
    __syncthreads();
    int wave = t >> 6, lane = t & 63;
#pragma unroll
    for (int rr = 0; rr < 4; rr++) {
        int nl = wave * 4 + rr;
        int n = n0 + nl;
        float vv[12];
        float s = 0.f, s2 = 0.f;
#pragma unroll
        for (int k = 0; k < 12; k++) {
            float v = tile[lane + (k << 6)][nl];
            vv[k] = v; s += v; s2 += v * v;
        }
#pragma unroll
        for (int off = 32; off > 0; off >>= 1) {
            s  += __shfl_xor(s, off);
            s2 += __shfl_xor(s2, off);
        }
        float mu = s * (1.0f / 768.0f);
        float var = s2 * (1.0f / 768.0f) - mu * mu;
        float rs = rsqrtf(var + 1e-5f);
        float* op = out + ((size_t)b * 2048 + n) * 768;
#pragma unroll
        for (int k = 0; k < 12; k++) {
            int d = lane + (k << 6);
            op[d] = (vv[k] - mu) * rs * g[d] + bet[d];
        }
    }
}

extern "C" void kernel_launch(void* const* d_in, const int* in_sizes, int n_in,
                              void* d_out, int out_size, void* d_ws, size_t ws_size,
                              hipStream_t stream) {
    const float* x   = (const float*)d_in[0];
    const float* bf  = (const float*)d_in[1];
    const float* w1  = (const float*)d_in[2];
    const float* b1  = (const float*)d_in[3];
    const float* w2  = (const float*)d_in[4];
    const float* b2  = (const float*)d_in[5];
    const float* lng = (const float*)d_in[6];
    const float* lnb = (const float*)d_in[7];
    float* out = (float*)d_out;

    float* ctx  = (float*)d_ws;            // 16*768
    float* tbuf = ctx + 16 * 768;          // 16*768
    float* mod  = tbuf + 16 * 768;         // 16*24576
    float* xT   = mod + (size_t)16 * 24576; // 16*768*2048 floats = 96 MiB

    hipMemsetAsync(ctx, 0, 16 * 768 * sizeof(float), stream);
    hipMemsetAsync(mod, 0, (size_t)16 * 24576 * sizeof(float), stream);

    transpose_ctx_kernel<<<dim3(12, 32, 16), 256, 0, stream>>>(x, xT, ctx);
    mlp1_kernel<<<dim3(3, 16), 256, 0, stream>>>(ctx, w1, b1, tbuf);
    mlp2_kernel<<<dim3(96, 4), 256, 0, stream>>>(tbuf, w2, b2, mod);
    spectral_kernel<<<dim3(32, 12, 16), 256, 0, stream>>>(xT, bf, mod);
    ln_kernel<<<dim3(128, 16), 256, 0, stream>>>(xT, lng, lnb, out);
}